// Round 1
// baseline (669.256 us; speedup 1.0000x reference)
//
#include <hip/hip_runtime.h>
#include <hip/hip_bf16.h>
#include <math.h>

#define N_TOK 4096
#define DIM_V 1024
#define NEXP  8
#define HID   4096
#define NSLOT 9216

typedef short  s16x8 __attribute__((ext_vector_type(8)));
typedef unsigned short u16x8 __attribute__((ext_vector_type(8)));
typedef float  f32x4 __attribute__((ext_vector_type(4)));

// ---------------- workspace layout ----------------
constexpr size_t OFF_XB   = 0;                       // bf16 [4096][1024]
constexpr size_t OFF_WB   = OFF_XB + 8388608;        // bf16 [1024][1024]
constexpr size_t OFF_H2   = OFF_WB + 2097152;        // bf16 [9216][4096]
constexpr size_t OFF_PO   = OFF_H2 + 75497472;       // f32  [9216][1024]
constexpr size_t OFF_RK   = OFF_PO + 37748736;       // f64  [8][1024]
constexpr size_t OFF_KPP  = OFF_RK + 65536;          // f64  [8][1024]   (zeroed)
constexpr size_t OFF_SSQ  = OFF_KPP + 65536;         // f32  [4096]      (zeroed)
constexpr size_t OFF_CNT  = OFF_SSQ + 16384;         // int  [8] pad128  (zeroed)
constexpr size_t OFF_CUR  = OFF_CNT + 128;           // int  [8] pad128  (zeroed)
constexpr size_t OFF_TOK  = OFF_CUR + 128;           // int  [9216]      (zeroed)
constexpr size_t OFF_GSL  = OFF_TOK + 36864;         // f32  [9216]      (zeroed)
constexpr size_t ZERO_BEG = OFF_KPP;
constexpr size_t ZERO_END = OFF_GSL + 36864;
constexpr size_t OFF_OFFP = ZERO_END;                // int  [16]
constexpr size_t OFF_IDX2 = OFF_OFFP + 128;          // int  [4096][2]
constexpr size_t OFF_G2   = OFF_IDX2 + 32768;        // f32  [4096][2]
constexpr size_t OFF_INV  = OFF_G2 + 32768;          // int  [4096][2]
constexpr size_t WS_NEED  = OFF_INV + 32768;         // ~118 MiB

__device__ inline unsigned short f2bf(float f) {
  __hip_bfloat16 h = __float2bfloat16(f);
  return __builtin_bit_cast(unsigned short, h);
}

// ---------------- prep: fp32 -> bf16 for x and router_w ----------------
__global__ void k_prep(const float* __restrict__ x, const float* __restrict__ W,
                       unsigned short* __restrict__ xb, unsigned short* __restrict__ wb) {
  const int NX = (N_TOK * DIM_V) / 4, NW = (DIM_V * DIM_V) / 4;
  for (int i = blockIdx.x * blockDim.x + threadIdx.x; i < NX + NW;
       i += gridDim.x * blockDim.x) {
    const float4* s; unsigned short* d; int j;
    if (i < NX) { s = (const float4*)x; d = xb; j = i; }
    else        { s = (const float4*)W; d = wb; j = i - NX; }
    float4 v = s[j];
    ushort4 o; o.x = f2bf(v.x); o.y = f2bf(v.y); o.z = f2bf(v.z); o.w = f2bf(v.w);
    *(ushort4*)(d + (size_t)j * 4) = o;
  }
}

// ---------------- rope'd keys: rk = R^T k (fp64) ----------------
__global__ void k_ropekeys(const float* __restrict__ keys, const int* __restrict__ depth,
                           double* __restrict__ rk) {
  int i = threadIdx.x;
  if (i >= 512) return;
  int dep = depth[0];
  double p = pow(10000.0, (double)i / 512.0);
  float invf = 1.0f / (float)p;                  // np: 1/fl(pow)
  float ff = (float)dep * invf;                  // fp32 angle like reference
  float rr = (float)(15 - dep) * invf;
  float cf  = (float)cos((double)ff);
  float sf  = (float)sin((double)ff);
  float rcf = (float)cos((double)rr);
  float rsf = (float)sin((double)rr);
  for (int e = 0; e < NEXP; ++e) {
    double k1 = (double)keys[e * DIM_V + i];
    double k2 = (double)keys[e * DIM_V + 512 + i];
    rk[e * DIM_V + i]       = (double)cf  * k1 - (double)rsf * k2;
    rk[e * DIM_V + 512 + i] = (double)sf  * k1 + (double)rcf * k2;
  }
}

// ---------------- kpp[e][j] = sum_d W[d][j] * rk[e][d] (fp64) ----------------
__global__ __launch_bounds__(256) void k_colsum(const float* __restrict__ W,
                                                const double* __restrict__ rk,
                                                double* __restrict__ kpp) {
  int j  = blockIdx.x * 256 + threadIdx.x;   // 0..1023
  int d0 = blockIdx.y * 64;
  double acc[NEXP] = {};
  for (int dd = 0; dd < 64; ++dd) {
    int d = d0 + dd;
    double w = (double)W[(size_t)d * DIM_V + j];
#pragma unroll
    for (int e = 0; e < NEXP; ++e) acc[e] += w * rk[e * DIM_V + d];
  }
  for (int e = 0; e < NEXP; ++e) atomicAdd(&kpp[e * DIM_V + j], acc[e]);
}

// ---------------- q~ = x@W^T (bf16 MFMA), emit row sum-of-squares ----------------
__global__ __launch_bounds__(256) void k_qt(const unsigned short* __restrict__ xb,
                                            const unsigned short* __restrict__ wb,
                                            float* __restrict__ sumsq) {
  __shared__ alignas(16) unsigned short As[128][64];
  __shared__ alignas(16) unsigned short Bs[128][64];
  const int m0 = blockIdx.x * 128, n0 = blockIdx.y * 128;
  const int tid = threadIdx.x, wid = tid >> 6, lane = tid & 63;
  const int wr = (wid >> 1) * 64, wc = (wid & 1) * 64;
  f32x4 acc[4][4] = {};
  for (int k0 = 0; k0 < DIM_V; k0 += 64) {
    __syncthreads();
#pragma unroll
    for (int p = 0; p < 4; ++p) {
      int idx = p * 256 + tid, row = idx >> 3, c8 = idx & 7;
      u16x8 v = *(const u16x8*)(xb + (size_t)(m0 + row) * DIM_V + k0 + c8 * 8);
      *(u16x8*)&As[row][c8 * 8] = v;
    }
#pragma unroll
    for (int p = 0; p < 4; ++p) {
      int idx = p * 256 + tid, row = idx >> 3, c8 = idx & 7;
      u16x8 v = *(const u16x8*)(wb + (size_t)(n0 + row) * DIM_V + k0 + c8 * 8);
      *(u16x8*)&Bs[row][c8 * 8] = v;
    }
    __syncthreads();
#pragma unroll
    for (int kk = 0; kk < 64; kk += 32) {
      s16x8 af[4], bfv[4];
#pragma unroll
      for (int m = 0; m < 4; ++m)
        af[m] = *(const s16x8*)&As[wr + m * 16 + (lane & 15)][kk + (lane >> 4) * 8];
#pragma unroll
      for (int n = 0; n < 4; ++n)
        bfv[n] = *(const s16x8*)&Bs[wc + n * 16 + (lane & 15)][kk + (lane >> 4) * 8];
#pragma unroll
      for (int m = 0; m < 4; ++m)
#pragma unroll
        for (int n = 0; n < 4; ++n)
          acc[m][n] = __builtin_amdgcn_mfma_f32_16x16x32_bf16(af[m], bfv[n], acc[m][n], 0, 0, 0);
    }
  }
#pragma unroll
  for (int m = 0; m < 4; ++m)
#pragma unroll
    for (int j = 0; j < 4; ++j) {
      float s = 0.f;
#pragma unroll
      for (int n = 0; n < 4; ++n) { float v = acc[m][n][j]; s += v * v; }
      s += __shfl_xor(s, 1, 64); s += __shfl_xor(s, 2, 64);
      s += __shfl_xor(s, 4, 64); s += __shfl_xor(s, 8, 64);
      if ((lane & 15) == 0)
        atomicAdd(&sumsq[m0 + wr + m * 16 + (lane >> 4) * 4 + j], s);
    }
}

// ---------------- gating: fp64 logits, sigmoid, top-2 ----------------
__global__ __launch_bounds__(256) void k_gate(const float* __restrict__ x,
                                              const double* __restrict__ kpp,
                                              const float* __restrict__ sumsq,
                                              const float* __restrict__ bias,
                                              int* __restrict__ idx2, float* __restrict__ gates2,
                                              int* __restrict__ counts) {
  int wave = (blockIdx.x * 256 + threadIdx.x) >> 6;
  int lane = threadIdx.x & 63;
  if (wave >= N_TOK) return;
  const float4* xr = (const float4*)(x + (size_t)wave * DIM_V);
  double a[NEXP] = {};
#pragma unroll
  for (int j = 0; j < 4; ++j) {
    int c = lane + 64 * j;
    float4 v = xr[c];
#pragma unroll
    for (int e = 0; e < NEXP; ++e) {
      const double* kp = kpp + (size_t)e * DIM_V + c * 4;
      a[e] += (double)v.x * kp[0] + (double)v.y * kp[1] +
              (double)v.z * kp[2] + (double)v.w * kp[3];
    }
  }
#pragma unroll
  for (int e = 0; e < NEXP; ++e)
    for (int d = 1; d < 64; d <<= 1) a[e] += __shfl_xor(a[e], d, 64);
  if (lane == 0) {
    float s = rsqrtf(sumsq[wave] * (1.0f / 1024.0f) + 1.1920928955078125e-7f);
    float z[NEXP], b[NEXP];
#pragma unroll
    for (int e = 0; e < NEXP; ++e) {
      z[e] = (float)(a[e] * (double)s * (1.0 / 32.0));
      b[e] = z[e] + bias[e];
    }
    int i1 = 0;
    for (int e = 1; e < NEXP; ++e) if (b[e] > b[i1]) i1 = e;
    int i2 = -1;
    for (int e = 0; e < NEXP; ++e) if (e != i1 && (i2 < 0 || b[e] > b[i2])) i2 = e;
    float g1 = 1.f / (1.f + expf(-z[i1]));
    float g2 = 1.f / (1.f + expf(-z[i2]));
    float sm = fmaxf(g1 + g2, 1e-9f);
    idx2[wave * 2] = i1; idx2[wave * 2 + 1] = i2;
    gates2[wave * 2] = g1 / sm; gates2[wave * 2 + 1] = g2 / sm;
    atomicAdd(&counts[i1], 1); atomicAdd(&counts[i2], 1);
  }
}

// ---------------- padded prefix ----------------
__global__ void k_prefix(const int* __restrict__ counts, int* __restrict__ offp) {
  if (threadIdx.x == 0) {
    int off = 0;
    for (int e = 0; e < NEXP; ++e) { offp[e] = off; off += (counts[e] + 127) & ~127; }
    offp[NEXP] = off;
  }
}

// ---------------- scatter tokens to slots ----------------
__global__ void k_scatter(const int* __restrict__ idx2, const float* __restrict__ gates2,
                          const int* __restrict__ offp, int* __restrict__ cursor,
                          int* __restrict__ tok, float* __restrict__ gsl,
                          int* __restrict__ inv) {
  int n = blockIdx.x * 256 + threadIdx.x;
  if (n >= N_TOK) return;
  for (int r = 0; r < 2; ++r) {
    int e = idx2[n * 2 + r];
    int pos = atomicAdd(&cursor[e], 1);
    int slot = offp[e] + pos;
    tok[slot] = n; gsl[slot] = gates2[n * 2 + r]; inv[n * 2 + r] = slot;
  }
}

// ---------------- fc: h2[slot][h] = bf16(relu(x@fc^T)^2) ----------------
__global__ __launch_bounds__(256) void k_fc(const unsigned short* __restrict__ xb,
                                            const float* __restrict__ fc_w,
                                            const int* __restrict__ offp,
                                            const int* __restrict__ tok,
                                            unsigned short* __restrict__ h2) {
  int m0 = blockIdx.x * 128;
  if (m0 >= offp[NEXP]) return;
  int e = 0; while (e < NEXP - 1 && m0 >= offp[e + 1]) ++e;
  const int n0 = blockIdx.y * 128;
  const float* B = fc_w + (size_t)e * HID * DIM_V + (size_t)n0 * DIM_V;
  __shared__ alignas(16) unsigned short As[128][64];
  __shared__ alignas(16) unsigned short Bs[128][64];
  __shared__ int rowtok[128];
  const int tid = threadIdx.x, wid = tid >> 6, lane = tid & 63;
  const int wr = (wid >> 1) * 64, wc = (wid & 1) * 64;
  if (tid < 128) rowtok[tid] = tok[m0 + tid];
  f32x4 acc[4][4] = {};
  for (int k0 = 0; k0 < DIM_V; k0 += 64) {
    __syncthreads();
#pragma unroll
    for (int p = 0; p < 4; ++p) {
      int idx = p * 256 + tid, row = idx >> 3, c8 = idx & 7;
      u16x8 v = *(const u16x8*)(xb + (size_t)rowtok[row] * DIM_V + k0 + c8 * 8);
      *(u16x8*)&As[row][c8 * 8] = v;
    }
#pragma unroll
    for (int p = 0; p < 2; ++p) {
      int idx = p * 256 + tid, row = idx >> 2, c = idx & 3;
      const float4* s = (const float4*)(B + (size_t)row * DIM_V + k0 + c * 16);
      float4 u0 = s[0], u1 = s[1], u2 = s[2], u3 = s[3];
      u16x8 o0 = { f2bf(u0.x), f2bf(u0.y), f2bf(u0.z), f2bf(u0.w),
                   f2bf(u1.x), f2bf(u1.y), f2bf(u1.z), f2bf(u1.w) };
      u16x8 o1 = { f2bf(u2.x), f2bf(u2.y), f2bf(u2.z), f2bf(u2.w),
                   f2bf(u3.x), f2bf(u3.y), f2bf(u3.z), f2bf(u3.w) };
      *(u16x8*)&Bs[row][c * 16] = o0;
      *(u16x8*)&Bs[row][c * 16 + 8] = o1;
    }
    __syncthreads();
#pragma unroll
    for (int kk = 0; kk < 64; kk += 32) {
      s16x8 af[4], bfv[4];
#pragma unroll
      for (int m = 0; m < 4; ++m)
        af[m] = *(const s16x8*)&As[wr + m * 16 + (lane & 15)][kk + (lane >> 4) * 8];
#pragma unroll
      for (int n = 0; n < 4; ++n)
        bfv[n] = *(const s16x8*)&Bs[wc + n * 16 + (lane & 15)][kk + (lane >> 4) * 8];
#pragma unroll
      for (int m = 0; m < 4; ++m)
#pragma unroll
        for (int n = 0; n < 4; ++n)
          acc[m][n] = __builtin_amdgcn_mfma_f32_16x16x32_bf16(af[m], bfv[n], acc[m][n], 0, 0, 0);
    }
  }
#pragma unroll
  for (int m = 0; m < 4; ++m)
#pragma unroll
    for (int j = 0; j < 4; ++j) {
      int grow = m0 + wr + m * 16 + (lane >> 4) * 4 + j;
#pragma unroll
      for (int n = 0; n < 4; ++n) {
        float v = acc[m][n][j];
        v = v > 0.f ? v * v : 0.f;
        h2[(size_t)grow * HID + n0 + wc + n * 16 + (lane & 15)] = f2bf(v);
      }
    }
}

// ---------------- proj: pair_out[slot][d] = gate * (h2 @ proj^T) ----------------
__global__ __launch_bounds__(256) void k_proj(const unsigned short* __restrict__ h2,
                                              const float* __restrict__ proj_w,
                                              const int* __restrict__ offp,
                                              const float* __restrict__ gsl,
                                              float* __restrict__ po) {
  int m0 = blockIdx.x * 128;
  if (m0 >= offp[NEXP]) return;
  int e = 0; while (e < NEXP - 1 && m0 >= offp[e + 1]) ++e;
  const int n0 = blockIdx.y * 128;
  const float* B = proj_w + (size_t)e * DIM_V * HID + (size_t)n0 * HID;
  __shared__ alignas(16) unsigned short As[128][64];
  __shared__ alignas(16) unsigned short Bs[128][64];
  const int tid = threadIdx.x, wid = tid >> 6, lane = tid & 63;
  const int wr = (wid >> 1) * 64, wc = (wid & 1) * 64;
  f32x4 acc[4][4] = {};
  for (int k0 = 0; k0 < HID; k0 += 64) {
    __syncthreads();
#pragma unroll
    for (int p = 0; p < 4; ++p) {
      int idx = p * 256 + tid, row = idx >> 3, c8 = idx & 7;
      u16x8 v = *(const u16x8*)(h2 + (size_t)(m0 + row) * HID + k0 + c8 * 8);
      *(u16x8*)&As[row][c8 * 8] = v;
    }
#pragma unroll
    for (int p = 0; p < 2; ++p) {
      int idx = p * 256 + tid, row = idx >> 2, c = idx & 3;
      const float4* s = (const float4*)(B + (size_t)row * HID + k0 + c * 16);
      float4 u0 = s[0], u1 = s[1], u2 = s[2], u3 = s[3];
      u16x8 o0 = { f2bf(u0.x), f2bf(u0.y), f2bf(u0.z), f2bf(u0.w),
                   f2bf(u1.x), f2bf(u1.y), f2bf(u1.z), f2bf(u1.w) };
      u16x8 o1 = { f2bf(u2.x), f2bf(u2.y), f2bf(u2.z), f2bf(u2.w),
                   f2bf(u3.x), f2bf(u3.y), f2bf(u3.z), f2bf(u3.w) };
      *(u16x8*)&Bs[row][c * 16] = o0;
      *(u16x8*)&Bs[row][c * 16 + 8] = o1;
    }
    __syncthreads();
#pragma unroll
    for (int kk = 0; kk < 64; kk += 32) {
      s16x8 af[4], bfv[4];
#pragma unroll
      for (int m = 0; m < 4; ++m)
        af[m] = *(const s16x8*)&As[wr + m * 16 + (lane & 15)][kk + (lane >> 4) * 8];
#pragma unroll
      for (int n = 0; n < 4; ++n)
        bfv[n] = *(const s16x8*)&Bs[wc + n * 16 + (lane & 15)][kk + (lane >> 4) * 8];
#pragma unroll
      for (int m = 0; m < 4; ++m)
#pragma unroll
        for (int n = 0; n < 4; ++n)
          acc[m][n] = __builtin_amdgcn_mfma_f32_16x16x32_bf16(af[m], bfv[n], acc[m][n], 0, 0, 0);
    }
  }
#pragma unroll
  for (int m = 0; m < 4; ++m)
#pragma unroll
    for (int j = 0; j < 4; ++j) {
      int grow = m0 + wr + m * 16 + (lane >> 4) * 4 + j;
      float g = gsl[grow];
#pragma unroll
      for (int n = 0; n < 4; ++n)
        po[(size_t)grow * DIM_V + n0 + wc + n * 16 + (lane & 15)] = acc[m][n][j] * g;
    }
}

// ---------------- combine: y[n] = po[slot1] + po[slot2] ----------------
__global__ void k_combine(const float* __restrict__ po, const int* __restrict__ inv,
                          float* __restrict__ y) {
  const int total = N_TOK * (DIM_V / 4);
  for (int i = blockIdx.x * blockDim.x + threadIdx.x; i < total;
       i += gridDim.x * blockDim.x) {
    int n = i >> 8, c = i & 255;
    int s1 = inv[n * 2], s2 = inv[n * 2 + 1];
    float4 a = ((const float4*)(po + (size_t)s1 * DIM_V))[c];
    float4 b = ((const float4*)(po + (size_t)s2 * DIM_V))[c];
    float4 o; o.x = a.x + b.x; o.y = a.y + b.y; o.z = a.z + b.z; o.w = a.w + b.w;
    ((float4*)(y + (size_t)n * DIM_V))[c] = o;
  }
}

extern "C" void kernel_launch(void* const* d_in, const int* in_sizes, int n_in,
                              void* d_out, int out_size, void* d_ws, size_t ws_size,
                              hipStream_t stream) {
  if (ws_size < WS_NEED) return;  // signature: output stays zero -> absmax == max|ref|
  const float* x      = (const float*)d_in[0];
  const float* rw     = (const float*)d_in[1];
  const float* keys   = (const float*)d_in[2];
  const float* bias   = (const float*)d_in[3];
  const float* fc_w   = (const float*)d_in[4];
  const float* proj_w = (const float*)d_in[5];
  const int*   depth  = (const int*)d_in[6];
  char* ws = (char*)d_ws;
  unsigned short* xb  = (unsigned short*)(ws + OFF_XB);
  unsigned short* wb  = (unsigned short*)(ws + OFF_WB);
  unsigned short* h2  = (unsigned short*)(ws + OFF_H2);
  float*  po    = (float*)(ws + OFF_PO);
  double* rk    = (double*)(ws + OFF_RK);
  double* kpp   = (double*)(ws + OFF_KPP);
  float*  ssq   = (float*)(ws + OFF_SSQ);
  int*    cnt   = (int*)(ws + OFF_CNT);
  int*    cur   = (int*)(ws + OFF_CUR);
  int*    tok   = (int*)(ws + OFF_TOK);
  float*  gsl   = (float*)(ws + OFF_GSL);
  int*    offp  = (int*)(ws + OFF_OFFP);
  int*    idx2  = (int*)(ws + OFF_IDX2);
  float*  g2    = (float*)(ws + OFF_G2);
  int*    inv   = (int*)(ws + OFF_INV);
  float*  y     = (float*)d_out;

  hipMemsetAsync(ws + ZERO_BEG, 0, ZERO_END - ZERO_BEG, stream);
  k_prep<<<2048, 256, 0, stream>>>(x, rw, xb, wb);
  k_ropekeys<<<1, 512, 0, stream>>>(keys, depth, rk);
  k_colsum<<<dim3(4, 16), 256, 0, stream>>>(rw, rk, kpp);
  k_qt<<<dim3(32, 8), 256, 0, stream>>>(xb, wb, ssq);
  k_gate<<<1024, 256, 0, stream>>>(x, kpp, ssq, bias, idx2, g2, cnt);
  k_prefix<<<1, 64, 0, stream>>>(cnt, offp);
  k_scatter<<<16, 256, 0, stream>>>(idx2, g2, offp, cur, tok, gsl, inv);
  k_fc<<<dim3(NSLOT / 128, HID / 128), 256, 0, stream>>>(xb, fc_w, offp, tok, h2);
  k_proj<<<dim3(NSLOT / 128, DIM_V / 128), 256, 0, stream>>>(h2, proj_w, offp, gsl, po);
  k_combine<<<2048, 256, 0, stream>>>(po, inv, y);
}

// Round 2
// 574.271 us; speedup vs baseline: 1.1654x; 1.1654x over previous
//
#include <hip/hip_runtime.h>
#include <hip/hip_bf16.h>
#include <math.h>

#define N_TOK 4096
#define DIM_V 1024
#define NEXP  8
#define HID   4096
#define NSLOT 9216

typedef short  s16x8 __attribute__((ext_vector_type(8)));
typedef unsigned short u16x8 __attribute__((ext_vector_type(8)));
typedef float  f32x4 __attribute__((ext_vector_type(4)));

// ---------------- workspace layout ----------------
// common small region
constexpr size_t OFF_XB   = 0;                        // bf16 [4096][1024]
constexpr size_t OFF_WB   = OFF_XB + 8388608;         // bf16 [1024][1024]
constexpr size_t OFF_RK   = OFF_WB + 2097152;         // f64  [8][1024]
constexpr size_t OFF_KPP  = OFF_RK + 65536;           // f64  [8][1024]  (zeroed)
constexpr size_t OFF_SSQ  = OFF_KPP + 65536;          // f32  [4096]     (zeroed)
constexpr size_t OFF_CNT  = OFF_SSQ + 16384;          // int[8] pad      (zeroed)
constexpr size_t OFF_CUR  = OFF_CNT + 128;            // int[8] pad      (zeroed)
constexpr size_t OFF_TOK  = OFF_CUR + 128;            // int  [9216]     (zeroed)
constexpr size_t OFF_GSL  = OFF_TOK + 36864;          // f32  [9216]     (zeroed)
constexpr size_t ZERO_BEG = OFF_KPP;
constexpr size_t ZERO_END = OFF_GSL + 36864;
constexpr size_t OFF_OFFP = ZERO_END;                 // int [16]
constexpr size_t OFF_IDX2 = OFF_OFFP + 128;           // int [4096][2]
constexpr size_t OFF_G2   = OFF_IDX2 + 32768;         // f32 [4096][2]
constexpr size_t OFF_INV  = OFF_G2 + 32768;           // int [4096][2]
constexpr size_t SMALL_END = OFF_INV + 32768;         // ~10.8 MiB

// tier A (bf16 weights): po aliases fcb (fc done before proj starts)
constexpr size_t A_OFF_FCB = SMALL_END;                    // bf16 [8][4096][1024]
constexpr size_t A_OFF_PO  = A_OFF_FCB;                    // f32  [9216][1024] (alias)
constexpr size_t A_OFF_PJB = A_OFF_FCB + 67108864;         // bf16 [8][1024][4096]
constexpr size_t A_OFF_H2  = A_OFF_PJB + 67108864;         // bf16 [9216][4096]
constexpr size_t WS_FULL   = A_OFF_H2 + 75497472;          // ~210.3 MiB

// tier B (fp32 weights read directly)
constexpr size_t B_OFF_PO  = SMALL_END;                    // f32  [9216][1024]
constexpr size_t B_OFF_H2  = B_OFF_PO + 37748736;          // bf16 [9216][4096]
constexpr size_t WS_BASE   = B_OFF_H2 + 75497472;          // ~118.3 MiB

__device__ inline unsigned short f2bf(float f) {
  __hip_bfloat16 h = __float2bfloat16(f);
  return __builtin_bit_cast(unsigned short, h);
}

__device__ __forceinline__ void gload16(const void* g, void* l) {
  __builtin_amdgcn_global_load_lds(
      (const __attribute__((address_space(1))) unsigned int*)g,
      (__attribute__((address_space(3))) unsigned int*)l, 16, 0, 0);
}

// ---------------- fp32 -> bf16 bulk convert ----------------
__global__ void k_cvt(const float* __restrict__ s, unsigned short* __restrict__ d, int n8) {
  for (int i = blockIdx.x * blockDim.x + threadIdx.x; i < n8;
       i += gridDim.x * blockDim.x) {
    float4 a = ((const float4*)s)[2 * i];
    float4 b = ((const float4*)s)[2 * i + 1];
    u16x8 o = { f2bf(a.x), f2bf(a.y), f2bf(a.z), f2bf(a.w),
                f2bf(b.x), f2bf(b.y), f2bf(b.z), f2bf(b.w) };
    *(u16x8*)(d + (size_t)i * 8) = o;
  }
}

// ---------------- rope'd keys: rk = R^T k (fp64) ----------------
__global__ void k_ropekeys(const float* __restrict__ keys, const int* __restrict__ depth,
                           double* __restrict__ rk) {
  int i = threadIdx.x;
  if (i >= 512) return;
  int dep = depth[0];
  double p = pow(10000.0, (double)i / 512.0);
  float invf = 1.0f / (float)p;
  float ff = (float)dep * invf;
  float rr = (float)(15 - dep) * invf;
  float cf  = (float)cos((double)ff);
  float sf  = (float)sin((double)ff);
  float rcf = (float)cos((double)rr);
  float rsf = (float)sin((double)rr);
  for (int e = 0; e < NEXP; ++e) {
    double k1 = (double)keys[e * DIM_V + i];
    double k2 = (double)keys[e * DIM_V + 512 + i];
    rk[e * DIM_V + i]       = (double)cf  * k1 - (double)rsf * k2;
    rk[e * DIM_V + 512 + i] = (double)sf  * k1 + (double)rcf * k2;
  }
}

// ---------------- kpp[e][j] = sum_d W[d][j] * rk[e][d] (fp64) ----------------
__global__ __launch_bounds__(256) void k_colsum(const float* __restrict__ W,
                                                const double* __restrict__ rk,
                                                double* __restrict__ kpp) {
  int j  = blockIdx.x * 256 + threadIdx.x;
  int d0 = blockIdx.y * 64;
  double acc[NEXP] = {};
  for (int dd = 0; dd < 64; ++dd) {
    int d = d0 + dd;
    double w = (double)W[(size_t)d * DIM_V + j];
#pragma unroll
    for (int e = 0; e < NEXP; ++e) acc[e] += w * rk[e * DIM_V + d];
  }
  for (int e = 0; e < NEXP; ++e) atomicAdd(&kpp[e * DIM_V + j], acc[e]);
}

// ---------------- q~ = x@W^T (bf16 MFMA), emit row sum-of-squares ----------------
__global__ __launch_bounds__(256) void k_qt(const unsigned short* __restrict__ xb,
                                            const unsigned short* __restrict__ wb,
                                            float* __restrict__ sumsq) {
  __shared__ alignas(16) unsigned short As[128][64];
  __shared__ alignas(16) unsigned short Bs[128][64];
  const int m0 = blockIdx.x * 128, n0 = blockIdx.y * 128;
  const int tid = threadIdx.x, wid = tid >> 6, lane = tid & 63;
  const int wr = (wid >> 1) * 64, wc = (wid & 1) * 64;
  const int srow = tid >> 3, scol = (tid & 7) * 8;
  f32x4 acc[4][4] = {};
  for (int k0 = 0; k0 < DIM_V; k0 += 64) {
    __syncthreads();
#pragma unroll
    for (int p = 0; p < 4; ++p)
      gload16(xb + (size_t)(m0 + p * 32 + srow) * DIM_V + k0 + scol,
              (char*)As + p * 4096 + wid * 1024);
#pragma unroll
    for (int p = 0; p < 4; ++p)
      gload16(wb + (size_t)(n0 + p * 32 + srow) * DIM_V + k0 + scol,
              (char*)Bs + p * 4096 + wid * 1024);
    __syncthreads();
#pragma unroll
    for (int kk = 0; kk < 64; kk += 32) {
      s16x8 af[4], bfv[4];
#pragma unroll
      for (int m = 0; m < 4; ++m)
        af[m] = *(const s16x8*)&As[wr + m * 16 + (lane & 15)][kk + (lane >> 4) * 8];
#pragma unroll
      for (int n = 0; n < 4; ++n)
        bfv[n] = *(const s16x8*)&Bs[wc + n * 16 + (lane & 15)][kk + (lane >> 4) * 8];
#pragma unroll
      for (int m = 0; m < 4; ++m)
#pragma unroll
        for (int n = 0; n < 4; ++n)
          acc[m][n] = __builtin_amdgcn_mfma_f32_16x16x32_bf16(af[m], bfv[n], acc[m][n], 0, 0, 0);
    }
  }
#pragma unroll
  for (int m = 0; m < 4; ++m)
#pragma unroll
    for (int j = 0; j < 4; ++j) {
      float s = 0.f;
#pragma unroll
      for (int n = 0; n < 4; ++n) { float v = acc[m][n][j]; s += v * v; }
      s += __shfl_xor(s, 1, 64); s += __shfl_xor(s, 2, 64);
      s += __shfl_xor(s, 4, 64); s += __shfl_xor(s, 8, 64);
      if ((lane & 15) == 0)
        atomicAdd(&sumsq[m0 + wr + m * 16 + (lane >> 4) * 4 + j], s);
    }
}

// ---------------- gating: fp64 logits, sigmoid, top-2 ----------------
__global__ __launch_bounds__(256) void k_gate(const float* __restrict__ x,
                                              const double* __restrict__ kpp,
                                              const float* __restrict__ sumsq,
                                              const float* __restrict__ bias,
                                              int* __restrict__ idx2, float* __restrict__ gates2,
                                              int* __restrict__ counts) {
  int wave = (blockIdx.x * 256 + threadIdx.x) >> 6;
  int lane = threadIdx.x & 63;
  if (wave >= N_TOK) return;
  const float4* xr = (const float4*)(x + (size_t)wave * DIM_V);
  double a[NEXP] = {};
#pragma unroll
  for (int j = 0; j < 4; ++j) {
    int c = lane + 64 * j;
    float4 v = xr[c];
#pragma unroll
    for (int e = 0; e < NEXP; ++e) {
      const double* kp = kpp + (size_t)e * DIM_V + c * 4;
      a[e] += (double)v.x * kp[0] + (double)v.y * kp[1] +
              (double)v.z * kp[2] + (double)v.w * kp[3];
    }
  }
#pragma unroll
  for (int e = 0; e < NEXP; ++e)
    for (int d = 1; d < 64; d <<= 1) a[e] += __shfl_xor(a[e], d, 64);
  if (lane == 0) {
    float s = rsqrtf(sumsq[wave] * (1.0f / 1024.0f) + 1.1920928955078125e-7f);
    float z[NEXP], b[NEXP];
#pragma unroll
    for (int e = 0; e < NEXP; ++e) {
      z[e] = (float)(a[e] * (double)s * (1.0 / 32.0));
      b[e] = z[e] + bias[e];
    }
    int i1 = 0;
    for (int e = 1; e < NEXP; ++e) if (b[e] > b[i1]) i1 = e;
    int i2 = -1;
    for (int e = 0; e < NEXP; ++e) if (e != i1 && (i2 < 0 || b[e] > b[i2])) i2 = e;
    float g1 = 1.f / (1.f + expf(-z[i1]));
    float g2 = 1.f / (1.f + expf(-z[i2]));
    float sm = fmaxf(g1 + g2, 1e-9f);
    idx2[wave * 2] = i1; idx2[wave * 2 + 1] = i2;
    gates2[wave * 2] = g1 / sm; gates2[wave * 2 + 1] = g2 / sm;
    atomicAdd(&counts[i1], 1); atomicAdd(&counts[i2], 1);
  }
}

// ---------------- padded prefix ----------------
__global__ void k_prefix(const int* __restrict__ counts, int* __restrict__ offp) {
  if (threadIdx.x == 0) {
    int off = 0;
    for (int e = 0; e < NEXP; ++e) { offp[e] = off; off += (counts[e] + 127) & ~127; }
    offp[NEXP] = off;
  }
}

// ---------------- scatter tokens to slots ----------------
__global__ void k_scatter(const int* __restrict__ idx2, const float* __restrict__ gates2,
                          const int* __restrict__ offp, int* __restrict__ cursor,
                          int* __restrict__ tok, float* __restrict__ gsl,
                          int* __restrict__ inv) {
  int n = blockIdx.x * 256 + threadIdx.x;
  if (n >= N_TOK) return;
  for (int r = 0; r < 2; ++r) {
    int e = idx2[n * 2 + r];
    int pos = atomicAdd(&cursor[e], 1);
    int slot = offp[e] + pos;
    tok[slot] = n; gsl[slot] = gates2[n * 2 + r]; inv[n * 2 + r] = slot;
  }
}

// ---------------- fc: h2[slot][h] = bf16(relu(x@fc^T)^2) ----------------
template<bool BBF16>
__global__ __launch_bounds__(256) void k_fc(const unsigned short* __restrict__ xb,
                                            const void* __restrict__ Bw,
                                            const int* __restrict__ offp,
                                            const int* __restrict__ tok,
                                            unsigned short* __restrict__ h2) {
  constexpr int GNB = HID / 128;  // 32
  const int G = gridDim.x;
  const int q = G >> 3, r = G & 7;
  const int xc = blockIdx.x & 7, ps = blockIdx.x >> 3;
  const int idp = (xc < r ? xc * (q + 1) : r * (q + 1) + (xc - r) * q) + ps;
  const int n0 = (idp % GNB) * 128;
  const int m0 = (idp / GNB) * 128;
  if (m0 >= offp[NEXP]) return;
  int e = 0; while (e < NEXP - 1 && m0 >= offp[e + 1]) ++e;
  __shared__ alignas(16) unsigned short As[128][64];
  __shared__ alignas(16) unsigned short Bs[128][64];
  const int tid = threadIdx.x, wid = tid >> 6, lane = tid & 63;
  const int wr = (wid >> 1) * 64, wc = (wid & 1) * 64;
  const int srow = tid >> 3, scol = (tid & 7) * 8;
  int tokA[4];
#pragma unroll
  for (int p = 0; p < 4; ++p) tokA[p] = tok[m0 + p * 32 + srow];
  f32x4 acc[4][4] = {};
  for (int k0 = 0; k0 < DIM_V; k0 += 64) {
    __syncthreads();
#pragma unroll
    for (int p = 0; p < 4; ++p)
      gload16(xb + (size_t)tokA[p] * DIM_V + k0 + scol,
              (char*)As + p * 4096 + wid * 1024);
    if constexpr (BBF16) {
      const unsigned short* Bp = (const unsigned short*)Bw
          + (size_t)e * HID * DIM_V + (size_t)n0 * DIM_V;
#pragma unroll
      for (int p = 0; p < 4; ++p)
        gload16(Bp + (size_t)(p * 32 + srow) * DIM_V + k0 + scol,
                (char*)Bs + p * 4096 + wid * 1024);
    } else {
      const float* Bp = (const float*)Bw + (size_t)e * HID * DIM_V + (size_t)n0 * DIM_V;
#pragma unroll
      for (int p = 0; p < 2; ++p) {
        int idx = p * 256 + tid, row = idx >> 2, c = idx & 3;
        const float4* s = (const float4*)(Bp + (size_t)row * DIM_V + k0 + c * 16);
        float4 u0 = s[0], u1 = s[1], u2 = s[2], u3 = s[3];
        u16x8 o0 = { f2bf(u0.x), f2bf(u0.y), f2bf(u0.z), f2bf(u0.w),
                     f2bf(u1.x), f2bf(u1.y), f2bf(u1.z), f2bf(u1.w) };
        u16x8 o1 = { f2bf(u2.x), f2bf(u2.y), f2bf(u2.z), f2bf(u2.w),
                     f2bf(u3.x), f2bf(u3.y), f2bf(u3.z), f2bf(u3.w) };
        *(u16x8*)&Bs[row][c * 16] = o0;
        *(u16x8*)&Bs[row][c * 16 + 8] = o1;
      }
    }
    __syncthreads();
#pragma unroll
    for (int kk = 0; kk < 64; kk += 32) {
      s16x8 af[4], bfv[4];
#pragma unroll
      for (int m = 0; m < 4; ++m)
        af[m] = *(const s16x8*)&As[wr + m * 16 + (lane & 15)][kk + (lane >> 4) * 8];
#pragma unroll
      for (int n = 0; n < 4; ++n)
        bfv[n] = *(const s16x8*)&Bs[wc + n * 16 + (lane & 15)][kk + (lane >> 4) * 8];
#pragma unroll
      for (int m = 0; m < 4; ++m)
#pragma unroll
        for (int n = 0; n < 4; ++n)
          acc[m][n] = __builtin_amdgcn_mfma_f32_16x16x32_bf16(af[m], bfv[n], acc[m][n], 0, 0, 0);
    }
  }
#pragma unroll
  for (int m = 0; m < 4; ++m)
#pragma unroll
    for (int j = 0; j < 4; ++j) {
      int grow = m0 + wr + m * 16 + (lane >> 4) * 4 + j;
#pragma unroll
      for (int n = 0; n < 4; ++n) {
        float v = acc[m][n][j];
        v = v > 0.f ? v * v : 0.f;
        h2[(size_t)grow * HID + n0 + wc + n * 16 + (lane & 15)] = f2bf(v);
      }
    }
}

// ---------------- proj: po[slot][d] = gate * (h2 @ proj^T) ----------------
template<bool BBF16>
__global__ __launch_bounds__(256) void k_proj(const unsigned short* __restrict__ h2,
                                              const void* __restrict__ Bw,
                                              const int* __restrict__ offp,
                                              const float* __restrict__ gsl,
                                              float* __restrict__ po) {
  constexpr int GNB = DIM_V / 128;  // 8
  const int G = gridDim.x;
  const int q = G >> 3, r = G & 7;
  const int xc = blockIdx.x & 7, ps = blockIdx.x >> 3;
  const int idp = (xc < r ? xc * (q + 1) : r * (q + 1) + (xc - r) * q) + ps;
  const int n0 = (idp % GNB) * 128;
  const int m0 = (idp / GNB) * 128;
  if (m0 >= offp[NEXP]) return;
  int e = 0; while (e < NEXP - 1 && m0 >= offp[e + 1]) ++e;
  __shared__ alignas(16) unsigned short As[128][64];
  __shared__ alignas(16) unsigned short Bs[128][64];
  const int tid = threadIdx.x, wid = tid >> 6, lane = tid & 63;
  const int wr = (wid >> 1) * 64, wc = (wid & 1) * 64;
  const int srow = tid >> 3, scol = (tid & 7) * 8;
  f32x4 acc[4][4] = {};
  for (int k0 = 0; k0 < HID; k0 += 64) {
    __syncthreads();
#pragma unroll
    for (int p = 0; p < 4; ++p)
      gload16(h2 + (size_t)(m0 + p * 32 + srow) * HID + k0 + scol,
              (char*)As + p * 4096 + wid * 1024);
    if constexpr (BBF16) {
      const unsigned short* Bp = (const unsigned short*)Bw
          + (size_t)e * DIM_V * HID + (size_t)n0 * HID;
#pragma unroll
      for (int p = 0; p < 4; ++p)
        gload16(Bp + (size_t)(p * 32 + srow) * HID + k0 + scol,
                (char*)Bs + p * 4096 + wid * 1024);
    } else {
      const float* Bp = (const float*)Bw + (size_t)e * DIM_V * HID + (size_t)n0 * HID;
#pragma unroll
      for (int p = 0; p < 2; ++p) {
        int idx = p * 256 + tid, row = idx >> 2, c = idx & 3;
        const float4* s = (const float4*)(Bp + (size_t)row * HID + k0 + c * 16);
        float4 u0 = s[0], u1 = s[1], u2 = s[2], u3 = s[3];
        u16x8 o0 = { f2bf(u0.x), f2bf(u0.y), f2bf(u0.z), f2bf(u0.w),
                     f2bf(u1.x), f2bf(u1.y), f2bf(u1.z), f2bf(u1.w) };
        u16x8 o1 = { f2bf(u2.x), f2bf(u2.y), f2bf(u2.z), f2bf(u2.w),
                     f2bf(u3.x), f2bf(u3.y), f2bf(u3.z), f2bf(u3.w) };
        *(u16x8*)&Bs[row][c * 16] = o0;
        *(u16x8*)&Bs[row][c * 16 + 8] = o1;
      }
    }
    __syncthreads();
#pragma unroll
    for (int kk = 0; kk < 64; kk += 32) {
      s16x8 af[4], bfv[4];
#pragma unroll
      for (int m = 0; m < 4; ++m)
        af[m] = *(const s16x8*)&As[wr + m * 16 + (lane & 15)][kk + (lane >> 4) * 8];
#pragma unroll
      for (int n = 0; n < 4; ++n)
        bfv[n] = *(const s16x8*)&Bs[wc + n * 16 + (lane & 15)][kk + (lane >> 4) * 8];
#pragma unroll
      for (int m = 0; m < 4; ++m)
#pragma unroll
        for (int n = 0; n < 4; ++n)
          acc[m][n] = __builtin_amdgcn_mfma_f32_16x16x32_bf16(af[m], bfv[n], acc[m][n], 0, 0, 0);
    }
  }
#pragma unroll
  for (int m = 0; m < 4; ++m)
#pragma unroll
    for (int j = 0; j < 4; ++j) {
      int grow = m0 + wr + m * 16 + (lane >> 4) * 4 + j;
      float g = gsl[grow];
#pragma unroll
      for (int n = 0; n < 4; ++n)
        po[(size_t)grow * DIM_V + n0 + wc + n * 16 + (lane & 15)] = acc[m][n][j] * g;
    }
}

// ---------------- combine: y[n] = po[slot1] + po[slot2] ----------------
__global__ void k_combine(const float* __restrict__ po, const int* __restrict__ inv,
                          float* __restrict__ y) {
  const int total = N_TOK * (DIM_V / 4);
  for (int i = blockIdx.x * blockDim.x + threadIdx.x; i < total;
       i += gridDim.x * blockDim.x) {
    int n = i >> 8, c = i & 255;
    int s1 = inv[n * 2], s2 = inv[n * 2 + 1];
    float4 a = ((const float4*)(po + (size_t)s1 * DIM_V))[c];
    float4 b = ((const float4*)(po + (size_t)s2 * DIM_V))[c];
    float4 o; o.x = a.x + b.x; o.y = a.y + b.y; o.z = a.z + b.z; o.w = a.w + b.w;
    ((float4*)(y + (size_t)n * DIM_V))[c] = o;
  }
}

extern "C" void kernel_launch(void* const* d_in, const int* in_sizes, int n_in,
                              void* d_out, int out_size, void* d_ws, size_t ws_size,
                              hipStream_t stream) {
  if (ws_size < WS_BASE) return;
  const bool full = (ws_size >= WS_FULL);
  const float* x      = (const float*)d_in[0];
  const float* rw     = (const float*)d_in[1];
  const float* keys   = (const float*)d_in[2];
  const float* bias   = (const float*)d_in[3];
  const float* fc_w   = (const float*)d_in[4];
  const float* proj_w = (const float*)d_in[5];
  const int*   depth  = (const int*)d_in[6];
  char* ws = (char*)d_ws;
  unsigned short* xb  = (unsigned short*)(ws + OFF_XB);
  unsigned short* wb  = (unsigned short*)(ws + OFF_WB);
  double* rk    = (double*)(ws + OFF_RK);
  double* kpp   = (double*)(ws + OFF_KPP);
  float*  ssq   = (float*)(ws + OFF_SSQ);
  int*    cnt   = (int*)(ws + OFF_CNT);
  int*    cur   = (int*)(ws + OFF_CUR);
  int*    tok   = (int*)(ws + OFF_TOK);
  float*  gsl   = (float*)(ws + OFF_GSL);
  int*    offp  = (int*)(ws + OFF_OFFP);
  int*    idx2  = (int*)(ws + OFF_IDX2);
  float*  g2    = (float*)(ws + OFF_G2);
  int*    inv   = (int*)(ws + OFF_INV);
  unsigned short* fcb = (unsigned short*)(ws + A_OFF_FCB);
  unsigned short* pjb = (unsigned short*)(ws + A_OFF_PJB);
  unsigned short* h2  = (unsigned short*)(ws + (full ? A_OFF_H2 : B_OFF_H2));
  float*  po    = (float*)(ws + (full ? A_OFF_PO : B_OFF_PO));
  float*  y     = (float*)d_out;

  hipMemsetAsync(ws + ZERO_BEG, 0, ZERO_END - ZERO_BEG, stream);
  k_cvt<<<1024, 256, 0, stream>>>(x,  xb, (N_TOK * DIM_V) / 8);
  k_cvt<<<512,  256, 0, stream>>>(rw, wb, (DIM_V * DIM_V) / 8);
  if (full) {
    k_cvt<<<2048, 256, 0, stream>>>(fc_w,   fcb, (NEXP * HID * DIM_V) / 8);
    k_cvt<<<2048, 256, 0, stream>>>(proj_w, pjb, (NEXP * DIM_V * HID) / 8);
  }
  k_ropekeys<<<1, 512, 0, stream>>>(keys, depth, rk);
  k_colsum<<<dim3(4, 16), 256, 0, stream>>>(rw, rk, kpp);
  k_qt<<<dim3(32, 8), 256, 0, stream>>>(xb, wb, ssq);
  k_gate<<<1024, 256, 0, stream>>>(x, kpp, ssq, bias, idx2, g2, cnt);
  k_prefix<<<1, 64, 0, stream>>>(cnt, offp);
  k_scatter<<<16, 256, 0, stream>>>(idx2, g2, offp, cur, tok, gsl, inv);
  if (full) {
    k_fc<true ><<<dim3((NSLOT / 128) * (HID / 128)), 256, 0, stream>>>(xb, fcb, offp, tok, h2);
    k_proj<true ><<<dim3((NSLOT / 128) * (DIM_V / 128)), 256, 0, stream>>>(h2, pjb, offp, gsl, po);
  } else {
    k_fc<false><<<dim3((NSLOT / 128) * (HID / 128)), 256, 0, stream>>>(xb, fc_w, offp, tok, h2);
    k_proj<false><<<dim3((NSLOT / 128) * (DIM_V / 128)), 256, 0, stream>>>(h2, proj_w, offp, gsl, po);
  }
  k_combine<<<2048, 256, 0, stream>>>(po, inv, y);
}

// Round 3
// 486.349 us; speedup vs baseline: 1.3761x; 1.1808x over previous
//
#include <hip/hip_runtime.h>
#include <hip/hip_bf16.h>
#include <math.h>

#define N_TOK 4096
#define DIM_V 1024
#define NEXP  8
#define HID   4096
#define NSLOT 9216

typedef short  s16x8 __attribute__((ext_vector_type(8)));
typedef unsigned short u16x8 __attribute__((ext_vector_type(8)));
typedef float  f32x4 __attribute__((ext_vector_type(4)));

// ---------------- workspace layout ----------------
constexpr size_t OFF_XB   = 0;                        // bf16 [4096][1024]
constexpr size_t OFF_WB   = OFF_XB + 8388608;         // bf16 [1024][1024]
constexpr size_t OFF_RK   = OFF_WB + 2097152;         // f64  [8][1024]
constexpr size_t OFF_KPP  = OFF_RK + 65536;           // f64  [8][1024]  (zeroed)
constexpr size_t OFF_SSQ  = OFF_KPP + 65536;          // f32  [4096]     (zeroed)
constexpr size_t OFF_CNT  = OFF_SSQ + 16384;          // int[8] pad      (zeroed)
constexpr size_t OFF_CUR  = OFF_CNT + 128;            // int[8] pad      (zeroed)
constexpr size_t OFF_TOK  = OFF_CUR + 128;            // int  [9216]     (zeroed)
constexpr size_t OFF_GSL  = OFF_TOK + 36864;          // f32  [9216]     (zeroed)
constexpr size_t ZERO_BEG = OFF_KPP;
constexpr size_t ZERO_END = OFF_GSL + 36864;
constexpr size_t OFF_OFFP = ZERO_END;                 // int [16]
constexpr size_t OFF_IDX2 = OFF_OFFP + 128;           // int [4096][2]
constexpr size_t OFF_G2   = OFF_IDX2 + 32768;         // f32 [4096][2]
constexpr size_t OFF_INV  = OFF_G2 + 32768;           // int [4096][2]
constexpr size_t SMALL_END = OFF_INV + 32768;

constexpr size_t A_OFF_FCB = SMALL_END;                    // bf16 [8][4096][1024]
constexpr size_t A_OFF_PO  = A_OFF_FCB;                    // f32  [9216][1024] (alias; fcb dead by then)
constexpr size_t A_OFF_PJB = A_OFF_FCB + 67108864;         // bf16 [8][1024][4096]
constexpr size_t A_OFF_H2  = A_OFF_PJB + 67108864;         // bf16 [9216][4096]
constexpr size_t WS_FULL   = A_OFF_H2 + 75497472;          // ~210.3 MiB (proven available in R2)

__device__ inline unsigned short f2bf(float f) {
  __hip_bfloat16 h = __float2bfloat16(f);
  return __builtin_bit_cast(unsigned short, h);
}

__device__ __forceinline__ void gload16(const void* g, void* l) {
  __builtin_amdgcn_global_load_lds(
      (const __attribute__((address_space(1))) unsigned int*)g,
      (__attribute__((address_space(3))) unsigned int*)l, 16, 0, 0);
}

// ---------------- fp32 -> bf16 bulk convert ----------------
__global__ void k_cvt(const float* __restrict__ s, unsigned short* __restrict__ d, int n8) {
  for (int i = blockIdx.x * blockDim.x + threadIdx.x; i < n8;
       i += gridDim.x * blockDim.x) {
    float4 a = ((const float4*)s)[2 * i];
    float4 b = ((const float4*)s)[2 * i + 1];
    u16x8 o = { f2bf(a.x), f2bf(a.y), f2bf(a.z), f2bf(a.w),
                f2bf(b.x), f2bf(b.y), f2bf(b.z), f2bf(b.w) };
    *(u16x8*)(d + (size_t)i * 8) = o;
  }
}

// ---------------- rope'd keys: rk = R^T k (fp64) ----------------
__global__ void k_ropekeys(const float* __restrict__ keys, const int* __restrict__ depth,
                           double* __restrict__ rk) {
  int i = threadIdx.x;
  if (i >= 512) return;
  int dep = depth[0];
  double p = pow(10000.0, (double)i / 512.0);
  float invf = 1.0f / (float)p;
  float ff = (float)dep * invf;
  float rr = (float)(15 - dep) * invf;
  float cf  = (float)cos((double)ff);
  float sf  = (float)sin((double)ff);
  float rcf = (float)cos((double)rr);
  float rsf = (float)sin((double)rr);
  for (int e = 0; e < NEXP; ++e) {
    double k1 = (double)keys[e * DIM_V + i];
    double k2 = (double)keys[e * DIM_V + 512 + i];
    rk[e * DIM_V + i]       = (double)cf  * k1 - (double)rsf * k2;
    rk[e * DIM_V + 512 + i] = (double)sf  * k1 + (double)rcf * k2;
  }
}

// ---------------- kpp[e][j] = sum_d W[d][j] * rk[e][d] (fp64) ----------------
__global__ __launch_bounds__(256) void k_colsum(const float* __restrict__ W,
                                                const double* __restrict__ rk,
                                                double* __restrict__ kpp) {
  int j  = blockIdx.x * 256 + threadIdx.x;
  int d0 = blockIdx.y * 64;
  double acc[NEXP] = {};
  for (int dd = 0; dd < 64; ++dd) {
    int d = d0 + dd;
    double w = (double)W[(size_t)d * DIM_V + j];
#pragma unroll
    for (int e = 0; e < NEXP; ++e) acc[e] += w * rk[e * DIM_V + d];
  }
  for (int e = 0; e < NEXP; ++e) atomicAdd(&kpp[e * DIM_V + j], acc[e]);
}

// ---------------- q~ = x@W^T (bf16 MFMA), emit row sum-of-squares ----------------
__global__ __launch_bounds__(256) void k_qt(const unsigned short* __restrict__ xb,
                                            const unsigned short* __restrict__ wb,
                                            float* __restrict__ sumsq) {
  __shared__ alignas(16) unsigned short As[128][64];
  __shared__ alignas(16) unsigned short Bs[128][64];
  const int m0 = blockIdx.x * 128, n0 = blockIdx.y * 128;
  const int tid = threadIdx.x, wid = tid >> 6, lane = tid & 63;
  const int wr = (wid >> 1) * 64, wc = (wid & 1) * 64;
  const int srow = tid >> 3, scol = (tid & 7) * 8;
  f32x4 acc[4][4] = {};
  for (int k0 = 0; k0 < DIM_V; k0 += 64) {
    __syncthreads();
#pragma unroll
    for (int p = 0; p < 4; ++p)
      gload16(xb + (size_t)(m0 + p * 32 + srow) * DIM_V + k0 + scol,
              (char*)As + p * 4096 + wid * 1024);
#pragma unroll
    for (int p = 0; p < 4; ++p)
      gload16(wb + (size_t)(n0 + p * 32 + srow) * DIM_V + k0 + scol,
              (char*)Bs + p * 4096 + wid * 1024);
    __syncthreads();
#pragma unroll
    for (int kk = 0; kk < 64; kk += 32) {
      s16x8 af[4], bfv[4];
#pragma unroll
      for (int m = 0; m < 4; ++m)
        af[m] = *(const s16x8*)&As[wr + m * 16 + (lane & 15)][kk + (lane >> 4) * 8];
#pragma unroll
      for (int n = 0; n < 4; ++n)
        bfv[n] = *(const s16x8*)&Bs[wc + n * 16 + (lane & 15)][kk + (lane >> 4) * 8];
#pragma unroll
      for (int m = 0; m < 4; ++m)
#pragma unroll
        for (int n = 0; n < 4; ++n)
          acc[m][n] = __builtin_amdgcn_mfma_f32_16x16x32_bf16(af[m], bfv[n], acc[m][n], 0, 0, 0);
    }
  }
#pragma unroll
  for (int m = 0; m < 4; ++m)
#pragma unroll
    for (int j = 0; j < 4; ++j) {
      float s = 0.f;
#pragma unroll
      for (int n = 0; n < 4; ++n) { float v = acc[m][n][j]; s += v * v; }
      s += __shfl_xor(s, 1, 64); s += __shfl_xor(s, 2, 64);
      s += __shfl_xor(s, 4, 64); s += __shfl_xor(s, 8, 64);
      if ((lane & 15) == 0)
        atomicAdd(&sumsq[m0 + wr + m * 16 + (lane >> 4) * 4 + j], s);
    }
}

// ---------------- gating: fp64 logits, sigmoid, top-2 ----------------
__global__ __launch_bounds__(256) void k_gate(const float* __restrict__ x,
                                              const double* __restrict__ kpp,
                                              const float* __restrict__ sumsq,
                                              const float* __restrict__ bias,
                                              int* __restrict__ idx2, float* __restrict__ gates2,
                                              int* __restrict__ counts) {
  int wave = (blockIdx.x * 256 + threadIdx.x) >> 6;
  int lane = threadIdx.x & 63;
  if (wave >= N_TOK) return;
  const float4* xr = (const float4*)(x + (size_t)wave * DIM_V);
  double a[NEXP] = {};
#pragma unroll
  for (int j = 0; j < 4; ++j) {
    int c = lane + 64 * j;
    float4 v = xr[c];
#pragma unroll
    for (int e = 0; e < NEXP; ++e) {
      const double* kp = kpp + (size_t)e * DIM_V + c * 4;
      a[e] += (double)v.x * kp[0] + (double)v.y * kp[1] +
              (double)v.z * kp[2] + (double)v.w * kp[3];
    }
  }
#pragma unroll
  for (int e = 0; e < NEXP; ++e)
    for (int d = 1; d < 64; d <<= 1) a[e] += __shfl_xor(a[e], d, 64);
  if (lane == 0) {
    float s = rsqrtf(sumsq[wave] * (1.0f / 1024.0f) + 1.1920928955078125e-7f);
    float z[NEXP], b[NEXP];
#pragma unroll
    for (int e = 0; e < NEXP; ++e) {
      z[e] = (float)(a[e] * (double)s * (1.0 / 32.0));
      b[e] = z[e] + bias[e];
    }
    int i1 = 0;
    for (int e = 1; e < NEXP; ++e) if (b[e] > b[i1]) i1 = e;
    int i2 = -1;
    for (int e = 0; e < NEXP; ++e) if (e != i1 && (i2 < 0 || b[e] > b[i2])) i2 = e;
    float g1 = 1.f / (1.f + expf(-z[i1]));
    float g2 = 1.f / (1.f + expf(-z[i2]));
    float sm = fmaxf(g1 + g2, 1e-9f);
    idx2[wave * 2] = i1; idx2[wave * 2 + 1] = i2;
    gates2[wave * 2] = g1 / sm; gates2[wave * 2 + 1] = g2 / sm;
    atomicAdd(&counts[i1], 1); atomicAdd(&counts[i2], 1);
  }
}

// ---------------- padded prefix ----------------
__global__ void k_prefix(const int* __restrict__ counts, int* __restrict__ offp) {
  if (threadIdx.x == 0) {
    int off = 0;
    for (int e = 0; e < NEXP; ++e) { offp[e] = off; off += (counts[e] + 127) & ~127; }
    offp[NEXP] = off;
  }
}

// ---------------- scatter tokens to slots ----------------
__global__ void k_scatter(const int* __restrict__ idx2, const float* __restrict__ gates2,
                          const int* __restrict__ offp, int* __restrict__ cursor,
                          int* __restrict__ tok, float* __restrict__ gsl,
                          int* __restrict__ inv) {
  int n = blockIdx.x * 256 + threadIdx.x;
  if (n >= N_TOK) return;
  for (int r = 0; r < 2; ++r) {
    int e = idx2[n * 2 + r];
    int pos = atomicAdd(&cursor[e], 1);
    int slot = offp[e] + pos;
    tok[slot] = n; gsl[slot] = gates2[n * 2 + r]; inv[n * 2 + r] = slot;
  }
}

// ================= grouped GEMM, 128x128x64, 4 waves =================
// counted-vmcnt double-buffer pipeline (T4), XOR-swizzled LDS (T2, both-sides
// via pre-swizzled global source for global_load_lds), raw s_barrier (no
// compiler vmcnt(0) drain), s_setprio around MFMA cluster (T5).
template<int KD, int ONB, bool GATHER, bool FCEPI>
__global__ __launch_bounds__(256) void k_gemm(
    const unsigned short* __restrict__ Aptr,   // xb (fc) / h2 (proj)
    const unsigned short* __restrict__ Wptr,   // fcb / pjb, [e][ONB][KD]
    const int* __restrict__ offp, const int* __restrict__ tok,
    const float* __restrict__ gsl, void* __restrict__ outp) {
  constexpr int GNB = ONB / 128;
  constexpr int NT  = KD / 64;
  const int G = gridDim.x, q = G >> 3;                  // G % 8 == 0
  const int idp = (blockIdx.x & 7) * q + (blockIdx.x >> 3);
  const int n0 = (idp % GNB) * 128, m0 = (idp / GNB) * 128;
  if (m0 >= offp[NEXP]) return;
  int e = 0; while (e < NEXP - 1 && m0 >= offp[e + 1]) ++e;
  const unsigned short* Bp = Wptr + ((size_t)e * ONB + n0) * KD;

  __shared__ alignas(16) char smem[65536];              // 2 bufs x (A 16K + B 16K)
  char* smb = smem;
  const int tid = threadIdx.x, wid = tid >> 6, lane = tid & 63;
  const int wr = (wid >> 1) * 64, wc = (wid & 1) * 64;
  const int rql  = tid >> 3;                            // staging row 0..31
  const int swc8 = ((tid & 7) ^ ((tid >> 3) & 7)) * 8;  // pre-swizzled src col (elems)
  const int frow = lane & 15, fsl = lane >> 4, fsw = lane & 7;

  int arow[4];
#pragma unroll
  for (int p = 0; p < 4; ++p)
    arow[p] = GATHER ? tok[m0 + p * 32 + rql] : (m0 + p * 32 + rql);

  auto stage = [&](int k0s, unsigned db) {
#pragma unroll
    for (int p = 0; p < 4; ++p)
      gload16(Aptr + (size_t)arow[p] * KD + k0s + swc8,
              smb + db + p * 4096 + wid * 1024);
#pragma unroll
    for (int p = 0; p < 4; ++p)
      gload16(Bp + (size_t)(p * 32 + rql) * KD + k0s + swc8,
              smb + db + 16384 + p * 4096 + wid * 1024);
  };

  f32x4 acc[4][4] = {};
  stage(0, 0);                                          // tile 0 -> buf 0
#pragma unroll 2
  for (int t = 0; t < NT; ++t) {
    int tn = t + 1; if (tn == NT) tn = 0;               // wrap: harmless reload
    stage(tn * 64, (unsigned)((t + 1) & 1) * 32768u);   // prefetch t+1
    asm volatile("s_waitcnt vmcnt(8)" ::: "memory");    // tile t landed; t+1 in flight
    __builtin_amdgcn_s_barrier();
    __builtin_amdgcn_sched_barrier(0);
    const unsigned Ab = (unsigned)(t & 1) * 32768u, Bb = Ab + 16384u;
    s16x8 af[2][4], bfr[2][4];
#pragma unroll
    for (int kk2 = 0; kk2 < 2; ++kk2) {
      const unsigned so = (unsigned)(((fsl + kk2 * 4) ^ fsw) << 4);
#pragma unroll
      for (int m = 0; m < 4; ++m)
        af[kk2][m] = *(const s16x8*)(smb + Ab + (unsigned)(wr + m * 16 + frow) * 128 + so);
#pragma unroll
      for (int n = 0; n < 4; ++n)
        bfr[kk2][n] = *(const s16x8*)(smb + Bb + (unsigned)(wc + n * 16 + frow) * 128 + so);
    }
    __builtin_amdgcn_s_setprio(1);
#pragma unroll
    for (int kk2 = 0; kk2 < 2; ++kk2)
#pragma unroll
      for (int m = 0; m < 4; ++m)
#pragma unroll
        for (int n = 0; n < 4; ++n)
          acc[m][n] = __builtin_amdgcn_mfma_f32_16x16x32_bf16(af[kk2][m], bfr[kk2][n],
                                                              acc[m][n], 0, 0, 0);
    __builtin_amdgcn_s_setprio(0);
    __builtin_amdgcn_sched_barrier(0);
    __builtin_amdgcn_s_barrier();                       // reads done -> buf reusable
  }

#pragma unroll
  for (int m = 0; m < 4; ++m)
#pragma unroll
    for (int j = 0; j < 4; ++j) {
      const int grow = m0 + wr + m * 16 + (lane >> 4) * 4 + j;
      if constexpr (FCEPI) {
        unsigned short* out = (unsigned short*)outp;
#pragma unroll
        for (int n = 0; n < 4; ++n) {
          float v = acc[m][n][j];
          v = v > 0.f ? v * v : 0.f;
          out[(size_t)grow * ONB + n0 + wc + n * 16 + (lane & 15)] = f2bf(v);
        }
      } else {
        float* out = (float*)outp;
        const float g = gsl[grow];
#pragma unroll
        for (int n = 0; n < 4; ++n)
          out[(size_t)grow * ONB + n0 + wc + n * 16 + (lane & 15)] = acc[m][n][j] * g;
      }
    }
}

// ---------------- combine: y[n] = po[slot1] + po[slot2] ----------------
__global__ void k_combine(const float* __restrict__ po, const int* __restrict__ inv,
                          float* __restrict__ y) {
  const int total = N_TOK * (DIM_V / 4);
  for (int i = blockIdx.x * blockDim.x + threadIdx.x; i < total;
       i += gridDim.x * blockDim.x) {
    int n = i >> 8, c = i & 255;
    int s1 = inv[n * 2], s2 = inv[n * 2 + 1];
    float4 a = ((const float4*)(po + (size_t)s1 * DIM_V))[c];
    float4 b = ((const float4*)(po + (size_t)s2 * DIM_V))[c];
    float4 o; o.x = a.x + b.x; o.y = a.y + b.y; o.z = a.z + b.z; o.w = a.w + b.w;
    ((float4*)(y + (size_t)n * DIM_V))[c] = o;
  }
}

extern "C" void kernel_launch(void* const* d_in, const int* in_sizes, int n_in,
                              void* d_out, int out_size, void* d_ws, size_t ws_size,
                              hipStream_t stream) {
  if (ws_size < WS_FULL) return;
  const float* x      = (const float*)d_in[0];
  const float* rw     = (const float*)d_in[1];
  const float* keys   = (const float*)d_in[2];
  const float* bias   = (const float*)d_in[3];
  const float* fc_w   = (const float*)d_in[4];
  const float* proj_w = (const float*)d_in[5];
  const int*   depth  = (const int*)d_in[6];
  char* ws = (char*)d_ws;
  unsigned short* xb  = (unsigned short*)(ws + OFF_XB);
  unsigned short* wb  = (unsigned short*)(ws + OFF_WB);
  double* rk    = (double*)(ws + OFF_RK);
  double* kpp   = (double*)(ws + OFF_KPP);
  float*  ssq   = (float*)(ws + OFF_SSQ);
  int*    cnt   = (int*)(ws + OFF_CNT);
  int*    cur   = (int*)(ws + OFF_CUR);
  int*    tok   = (int*)(ws + OFF_TOK);
  float*  gsl   = (float*)(ws + OFF_GSL);
  int*    offp  = (int*)(ws + OFF_OFFP);
  int*    idx2  = (int*)(ws + OFF_IDX2);
  float*  g2    = (float*)(ws + OFF_G2);
  int*    inv   = (int*)(ws + OFF_INV);
  unsigned short* fcb = (unsigned short*)(ws + A_OFF_FCB);
  unsigned short* pjb = (unsigned short*)(ws + A_OFF_PJB);
  unsigned short* h2  = (unsigned short*)(ws + A_OFF_H2);
  float*  po    = (float*)(ws + A_OFF_PO);
  float*  y     = (float*)d_out;

  hipMemsetAsync(ws + ZERO_BEG, 0, ZERO_END - ZERO_BEG, stream);
  k_cvt<<<1024, 256, 0, stream>>>(x,  xb, (N_TOK * DIM_V) / 8);
  k_cvt<<<512,  256, 0, stream>>>(rw, wb, (DIM_V * DIM_V) / 8);
  k_cvt<<<2048, 256, 0, stream>>>(fc_w,   fcb, (NEXP * HID * DIM_V) / 8);
  k_cvt<<<2048, 256, 0, stream>>>(proj_w, pjb, (NEXP * DIM_V * HID) / 8);
  k_ropekeys<<<1, 512, 0, stream>>>(keys, depth, rk);
  k_colsum<<<dim3(4, 16), 256, 0, stream>>>(rw, rk, kpp);
  k_qt<<<dim3(32, 8), 256, 0, stream>>>(xb, wb, ssq);
  k_gate<<<1024, 256, 0, stream>>>(x, kpp, ssq, bias, idx2, g2, cnt);
  k_prefix<<<1, 64, 0, stream>>>(cnt, offp);
  k_scatter<<<16, 256, 0, stream>>>(idx2, g2, offp, cur, tok, gsl, inv);
  k_gemm<DIM_V, HID,   true,  true ><<<dim3((NSLOT / 128) * (HID / 128)),   256, 0, stream>>>(
      xb, fcb, offp, tok, gsl, h2);
  k_gemm<HID,   DIM_V, false, false><<<dim3((NSLOT / 128) * (DIM_V / 128)), 256, 0, stream>>>(
      h2, pjb, offp, tok, gsl, po);
  k_combine<<<2048, 256, 0, stream>>>(po, inv, y);
}

// Round 4
// 473.784 us; speedup vs baseline: 1.4126x; 1.0265x over previous
//
#include <hip/hip_runtime.h>
#include <hip/hip_bf16.h>
#include <math.h>

#define N_TOK 4096
#define DIM_V 1024
#define NEXP  8
#define HID   4096
#define NSLOT 9216

typedef short  s16x8 __attribute__((ext_vector_type(8)));
typedef unsigned short u16x8 __attribute__((ext_vector_type(8)));
typedef float  f32x4 __attribute__((ext_vector_type(4)));

// ---------------- workspace layout ----------------
constexpr size_t OFF_XB   = 0;                        // bf16 [4096][1024]
constexpr size_t OFF_WB   = OFF_XB + 8388608;         // bf16 [1024][1024]
constexpr size_t OFF_RK   = OFF_WB + 2097152;         // f64  [8][1024]
constexpr size_t OFF_KPP  = OFF_RK + 65536;           // f64  [8][1024]  (zeroed)
constexpr size_t OFF_SSQ  = OFF_KPP + 65536;          // f32  [4096]     (zeroed)
constexpr size_t OFF_CNT  = OFF_SSQ + 16384;          // int[8] pad      (zeroed)
constexpr size_t OFF_CUR  = OFF_CNT + 128;            // int[8] pad      (zeroed)
constexpr size_t OFF_TOK  = OFF_CUR + 128;            // int  [9216]     (zeroed)
constexpr size_t OFF_GSL  = OFF_TOK + 36864;          // f32  [9216]     (zeroed)
constexpr size_t ZERO_BEG = OFF_KPP;
constexpr size_t ZERO_END = OFF_GSL + 36864;
constexpr size_t OFF_OFFP = ZERO_END;                 // int [16]
constexpr size_t OFF_IDX2 = OFF_OFFP + 128;           // int [4096][2]
constexpr size_t OFF_G2   = OFF_IDX2 + 32768;         // f32 [4096][2]
constexpr size_t OFF_INV  = OFF_G2 + 32768;           // int [4096][2]
constexpr size_t SMALL_END = OFF_INV + 32768;

constexpr size_t A_OFF_FCB = SMALL_END;                    // bf16 [8][4096][1024]
constexpr size_t A_OFF_PO  = A_OFF_FCB;                    // f32  [9216][1024] (alias; fcb dead)
constexpr size_t A_OFF_PJB = A_OFF_FCB + 67108864;         // bf16 [8][1024][4096]
constexpr size_t A_OFF_H2  = A_OFF_PJB + 67108864;         // bf16 [9216][4096]
constexpr size_t WS_FULL   = A_OFF_H2 + 75497472;          // ~210.3 MiB (proven)

__device__ inline unsigned short f2bf(float f) {
  __hip_bfloat16 h = __float2bfloat16(f);
  return __builtin_bit_cast(unsigned short, h);
}

__device__ __forceinline__ void gload16(const void* g, void* l) {
  __builtin_amdgcn_global_load_lds(
      (const __attribute__((address_space(1))) unsigned int*)g,
      (__attribute__((address_space(3))) unsigned int*)l, 16, 0, 0);
}

// ---------------- fused fp32 -> bf16 bulk convert (x, rw, fc_w, proj_w) ----------------
__global__ void k_cvt_all(const float* __restrict__ x, const float* __restrict__ rw,
                          const float* __restrict__ fw, const float* __restrict__ pw,
                          unsigned short* __restrict__ xb, unsigned short* __restrict__ wb,
                          unsigned short* __restrict__ fcb, unsigned short* __restrict__ pjb) {
  const int NX = (N_TOK * DIM_V) / 8, NW = (DIM_V * DIM_V) / 8;
  const int NF = (NEXP * HID * DIM_V) / 8;
  const int total = NX + NW + NF + NF;
  for (int i = blockIdx.x * blockDim.x + threadIdx.x; i < total;
       i += gridDim.x * blockDim.x) {
    const float* s; unsigned short* d; int j;
    if (i < NX)                { s = x;  d = xb;  j = i; }
    else if (i < NX + NW)      { s = rw; d = wb;  j = i - NX; }
    else if (i < NX + NW + NF) { s = fw; d = fcb; j = i - NX - NW; }
    else                       { s = pw; d = pjb; j = i - NX - NW - NF; }
    float4 a = ((const float4*)s)[2 * j];
    float4 b = ((const float4*)s)[2 * j + 1];
    u16x8 o = { f2bf(a.x), f2bf(a.y), f2bf(a.z), f2bf(a.w),
                f2bf(b.x), f2bf(b.y), f2bf(b.z), f2bf(b.w) };
    *(u16x8*)(d + (size_t)j * 8) = o;
  }
}

// ---------------- rope'd keys: rk = R^T k (fp64) ----------------
__global__ void k_ropekeys(const float* __restrict__ keys, const int* __restrict__ depth,
                           double* __restrict__ rk) {
  int i = threadIdx.x;
  if (i >= 512) return;
  int dep = depth[0];
  double p = pow(10000.0, (double)i / 512.0);
  float invf = 1.0f / (float)p;
  float ff = (float)dep * invf;
  float rr = (float)(15 - dep) * invf;
  float cf  = (float)cos((double)ff);
  float sf  = (float)sin((double)ff);
  float rcf = (float)cos((double)rr);
  float rsf = (float)sin((double)rr);
  for (int e = 0; e < NEXP; ++e) {
    double k1 = (double)keys[e * DIM_V + i];
    double k2 = (double)keys[e * DIM_V + 512 + i];
    rk[e * DIM_V + i]       = (double)cf  * k1 - (double)rsf * k2;
    rk[e * DIM_V + 512 + i] = (double)sf  * k1 + (double)rcf * k2;
  }
}

// ---------------- kpp[e][j] = sum_d W[d][j] * rk[e][d] (fp64) ----------------
__global__ __launch_bounds__(256) void k_colsum(const float* __restrict__ W,
                                                const double* __restrict__ rk,
                                                double* __restrict__ kpp) {
  int j  = blockIdx.x * 256 + threadIdx.x;
  int d0 = blockIdx.y * 64;
  double acc[NEXP] = {};
  for (int dd = 0; dd < 64; ++dd) {
    int d = d0 + dd;
    double w = (double)W[(size_t)d * DIM_V + j];
#pragma unroll
    for (int e = 0; e < NEXP; ++e) acc[e] += w * rk[e * DIM_V + d];
  }
  for (int e = 0; e < NEXP; ++e) atomicAdd(&kpp[e * DIM_V + j], acc[e]);
}

// ---------------- gating: fp64 logits, sigmoid, top-2 ----------------
__global__ __launch_bounds__(256) void k_gate(const float* __restrict__ x,
                                              const double* __restrict__ kpp,
                                              const float* __restrict__ sumsq,
                                              const float* __restrict__ bias,
                                              int* __restrict__ idx2, float* __restrict__ gates2,
                                              int* __restrict__ counts) {
  int wave = (blockIdx.x * 256 + threadIdx.x) >> 6;
  int lane = threadIdx.x & 63;
  if (wave >= N_TOK) return;
  const float4* xr = (const float4*)(x + (size_t)wave * DIM_V);
  double a[NEXP] = {};
#pragma unroll
  for (int j = 0; j < 4; ++j) {
    int c = lane + 64 * j;
    float4 v = xr[c];
#pragma unroll
    for (int e = 0; e < NEXP; ++e) {
      const double* kp = kpp + (size_t)e * DIM_V + c * 4;
      a[e] += (double)v.x * kp[0] + (double)v.y * kp[1] +
              (double)v.z * kp[2] + (double)v.w * kp[3];
    }
  }
#pragma unroll
  for (int e = 0; e < NEXP; ++e)
    for (int d = 1; d < 64; d <<= 1) a[e] += __shfl_xor(a[e], d, 64);
  if (lane == 0) {
    float s = rsqrtf(sumsq[wave] * (1.0f / 1024.0f) + 1.1920928955078125e-7f);
    float z[NEXP], b[NEXP];
#pragma unroll
    for (int e = 0; e < NEXP; ++e) {
      z[e] = (float)(a[e] * (double)s * (1.0 / 32.0));
      b[e] = z[e] + bias[e];
    }
    int i1 = 0;
    for (int e = 1; e < NEXP; ++e) if (b[e] > b[i1]) i1 = e;
    int i2 = -1;
    for (int e = 0; e < NEXP; ++e) if (e != i1 && (i2 < 0 || b[e] > b[i2])) i2 = e;
    float g1 = 1.f / (1.f + expf(-z[i1]));
    float g2 = 1.f / (1.f + expf(-z[i2]));
    float sm = fmaxf(g1 + g2, 1e-9f);
    idx2[wave * 2] = i1; idx2[wave * 2 + 1] = i2;
    gates2[wave * 2] = g1 / sm; gates2[wave * 2 + 1] = g2 / sm;
    atomicAdd(&counts[i1], 1); atomicAdd(&counts[i2], 1);
  }
}

// ---------------- scatter tokens to slots (prefix computed locally) ----------------
__global__ void k_scatter(const int* __restrict__ idx2, const float* __restrict__ gates2,
                          const int* __restrict__ counts, int* __restrict__ cursor,
                          int* __restrict__ tok, float* __restrict__ gsl,
                          int* __restrict__ inv, int* __restrict__ offp_out) {
  int off[NEXP + 1];
  off[0] = 0;
  for (int e = 0; e < NEXP; ++e) off[e + 1] = off[e] + ((counts[e] + 127) & ~127);
  int n = blockIdx.x * 256 + threadIdx.x;
  if (blockIdx.x == 0 && threadIdx.x == 0)
    for (int e = 0; e <= NEXP; ++e) offp_out[e] = off[e];
  if (n >= N_TOK) return;
  for (int r = 0; r < 2; ++r) {
    int e = idx2[n * 2 + r];
    int pos = atomicAdd(&cursor[e], 1);
    int slot = off[e] + pos;
    tok[slot] = n; gsl[slot] = gates2[n * 2 + r]; inv[n * 2 + r] = slot;
  }
}

// ================= fc: 256x256x64 grouped GEMM, 8 waves, 128KiB LDS =================
__global__ __launch_bounds__(512) void k_fc256(
    const unsigned short* __restrict__ xb,
    const unsigned short* __restrict__ fcb,
    const int* __restrict__ offp, const int* __restrict__ tok,
    unsigned short* __restrict__ h2) {
  constexpr int KD = DIM_V;     // 1024
  constexpr int NT = KD / 64;   // 16
  const int G = gridDim.x, q = G >> 3;                 // G % 8 == 0
  const int idp = ((int)blockIdx.x & 7) * q + ((int)blockIdx.x >> 3);
  const int bx = idp >> 4;                             // 256-row block index
  const int n0 = (idp & 15) * 256;
  int c = 0, e = 0, m0 = -1;
  for (e = 0; e < NEXP; ++e) {
    int nb = (offp[e + 1] - offp[e] + 255) >> 8;
    if (bx < c + nb) { m0 = offp[e] + (bx - c) * 256; break; }
    c += nb;
  }
  if (m0 < 0) return;
  const int segend = offp[e + 1];
  const unsigned short* Bp = fcb + ((size_t)e * HID + n0) * KD;

  __shared__ alignas(16) char smem[131072];            // 2 x (A 32K + B 32K)
  const int tid = threadIdx.x, wid = tid >> 6, lane = tid & 63;
  const int wr = (wid >> 2) * 128, wcc = (wid & 3) * 64;
  const int swc8 = ((tid & 7) ^ ((tid >> 3) & 7)) * 8;
  const int frow = lane & 15, fsl = lane >> 4, fkey = lane & 7;

  int arow[4];
#pragma unroll
  for (int p = 0; p < 4; ++p) {
    int rr = m0 + p * 64 + (tid >> 3);
    arow[p] = tok[rr < NSLOT ? rr : NSLOT - 1];
  }

  auto stage = [&](int k0s, unsigned db) {
#pragma unroll
    for (int p = 0; p < 4; ++p)
      gload16(xb + (size_t)arow[p] * KD + k0s + swc8,
              smem + db + p * 8192 + wid * 1024);
#pragma unroll
    for (int p = 0; p < 4; ++p)
      gload16(Bp + (size_t)(p * 64 + (tid >> 3)) * KD + k0s + swc8,
              smem + db + 32768 + p * 8192 + wid * 1024);
  };

  f32x4 acc[8][4] = {};
  stage(0, 0);
  for (int t = 0; t < NT; ++t) {
    int tn = t + 1; if (tn == NT) tn = 0;
    stage(tn * 64, (unsigned)((t + 1) & 1) * 65536u);
    asm volatile("s_waitcnt vmcnt(8)" ::: "memory");
    __builtin_amdgcn_s_barrier();
    __builtin_amdgcn_sched_barrier(0);
    const unsigned Ab = (unsigned)(t & 1) * 65536u, Bb = Ab + 32768u;
#pragma unroll
    for (int kk2 = 0; kk2 < 2; ++kk2) {
      const unsigned so = (unsigned)(((fsl + kk2 * 4) ^ fkey) << 4);
      s16x8 af[8], bfr[4];
#pragma unroll
      for (int m = 0; m < 8; ++m)
        af[m] = *(const s16x8*)(smem + Ab + (unsigned)(wr + m * 16 + frow) * 128 + so);
#pragma unroll
      for (int n = 0; n < 4; ++n)
        bfr[n] = *(const s16x8*)(smem + Bb + (unsigned)(wcc + n * 16 + frow) * 128 + so);
      __builtin_amdgcn_s_setprio(1);
#pragma unroll
      for (int m = 0; m < 8; ++m)
#pragma unroll
        for (int n = 0; n < 4; ++n)
          acc[m][n] = __builtin_amdgcn_mfma_f32_16x16x32_bf16(af[m], bfr[n], acc[m][n], 0, 0, 0);
      __builtin_amdgcn_s_setprio(0);
    }
    __builtin_amdgcn_sched_barrier(0);
    __builtin_amdgcn_s_barrier();
  }
#pragma unroll
  for (int m = 0; m < 8; ++m)
#pragma unroll
    for (int j = 0; j < 4; ++j) {
      const int grow = m0 + wr + m * 16 + (lane >> 4) * 4 + j;
      if (grow < segend) {
#pragma unroll
        for (int n = 0; n < 4; ++n) {
          float v = acc[m][n][j];
          v = v > 0.f ? v * v : 0.f;
          h2[(size_t)grow * HID + n0 + wcc + n * 16 + (lane & 15)] = f2bf(v);
        }
      }
    }
}

// ================= 128x128x64 GEMM, 4 waves: EPI 0 = sumsq (router), 1 = proj =================
template<int KD, int ONB, int EPI>
__global__ __launch_bounds__(256) void k_gemm(
    const unsigned short* __restrict__ Aptr,
    const unsigned short* __restrict__ Wptr,     // [e][ONB][KD] (e=0 for EPI 0)
    const int* __restrict__ offp,
    const float* __restrict__ gsl, void* __restrict__ outp) {
  constexpr int GNB = ONB / 128;
  constexpr int NT  = KD / 64;
  const int G = gridDim.x, q = G >> 3;
  const int idp = ((int)blockIdx.x & 7) * q + ((int)blockIdx.x >> 3);
  const int n0 = (idp % GNB) * 128, m0 = (idp / GNB) * 128;
  int e = 0;
  if constexpr (EPI == 1) {
    if (m0 >= offp[NEXP]) return;
    while (e < NEXP - 1 && m0 >= offp[e + 1]) ++e;
  }
  const unsigned short* Bp = Wptr + ((size_t)e * ONB + n0) * KD;

  __shared__ alignas(16) char smem[65536];
  const int tid = threadIdx.x, wid = tid >> 6, lane = tid & 63;
  const int wr = (wid >> 1) * 64, wc = (wid & 1) * 64;
  const int rql  = tid >> 3;
  const int swc8 = ((tid & 7) ^ ((tid >> 3) & 7)) * 8;
  const int frow = lane & 15, fsl = lane >> 4, fkey = lane & 7;

  auto stage = [&](int k0s, unsigned db) {
#pragma unroll
    for (int p = 0; p < 4; ++p)
      gload16(Aptr + (size_t)(m0 + p * 32 + rql) * KD + k0s + swc8,
              smem + db + p * 4096 + wid * 1024);
#pragma unroll
    for (int p = 0; p < 4; ++p)
      gload16(Bp + (size_t)(p * 32 + rql) * KD + k0s + swc8,
              smem + db + 16384 + p * 4096 + wid * 1024);
  };

  f32x4 acc[4][4] = {};
  stage(0, 0);
#pragma unroll 2
  for (int t = 0; t < NT; ++t) {
    int tn = t + 1; if (tn == NT) tn = 0;
    stage(tn * 64, (unsigned)((t + 1) & 1) * 32768u);
    asm volatile("s_waitcnt vmcnt(8)" ::: "memory");
    __builtin_amdgcn_s_barrier();
    __builtin_amdgcn_sched_barrier(0);
    const unsigned Ab = (unsigned)(t & 1) * 32768u, Bb = Ab + 16384u;
    s16x8 af[2][4], bfr[2][4];
#pragma unroll
    for (int kk2 = 0; kk2 < 2; ++kk2) {
      const unsigned so = (unsigned)(((fsl + kk2 * 4) ^ fkey) << 4);
#pragma unroll
      for (int m = 0; m < 4; ++m)
        af[kk2][m] = *(const s16x8*)(smem + Ab + (unsigned)(wr + m * 16 + frow) * 128 + so);
#pragma unroll
      for (int n = 0; n < 4; ++n)
        bfr[kk2][n] = *(const s16x8*)(smem + Bb + (unsigned)(wc + n * 16 + frow) * 128 + so);
    }
    __builtin_amdgcn_s_setprio(1);
#pragma unroll
    for (int kk2 = 0; kk2 < 2; ++kk2)
#pragma unroll
      for (int m = 0; m < 4; ++m)
#pragma unroll
        for (int n = 0; n < 4; ++n)
          acc[m][n] = __builtin_amdgcn_mfma_f32_16x16x32_bf16(af[kk2][m], bfr[kk2][n],
                                                              acc[m][n], 0, 0, 0);
    __builtin_amdgcn_s_setprio(0);
    __builtin_amdgcn_sched_barrier(0);
    __builtin_amdgcn_s_barrier();
  }

#pragma unroll
  for (int m = 0; m < 4; ++m)
#pragma unroll
    for (int j = 0; j < 4; ++j) {
      const int grow = m0 + wr + m * 16 + (lane >> 4) * 4 + j;
      if constexpr (EPI == 0) {
        float s = 0.f;
#pragma unroll
        for (int n = 0; n < 4; ++n) { float v = acc[m][n][j]; s += v * v; }
        s += __shfl_xor(s, 1, 64); s += __shfl_xor(s, 2, 64);
        s += __shfl_xor(s, 4, 64); s += __shfl_xor(s, 8, 64);
        if ((lane & 15) == 0) atomicAdd(&((float*)outp)[grow], s);
      } else {
        float* out = (float*)outp;
        const float g = gsl[grow];
#pragma unroll
        for (int n = 0; n < 4; ++n)
          out[(size_t)grow * ONB + n0 + wc + n * 16 + (lane & 15)] = acc[m][n][j] * g;
      }
    }
}

// ---------------- combine: y[n] = po[slot1] + po[slot2] ----------------
__global__ void k_combine(const float* __restrict__ po, const int* __restrict__ inv,
                          float* __restrict__ y) {
  const int total = N_TOK * (DIM_V / 4);
  for (int i = blockIdx.x * blockDim.x + threadIdx.x; i < total;
       i += gridDim.x * blockDim.x) {
    int n = i >> 8, c = i & 255;
    int s1 = inv[n * 2], s2 = inv[n * 2 + 1];
    float4 a = ((const float4*)(po + (size_t)s1 * DIM_V))[c];
    float4 b = ((const float4*)(po + (size_t)s2 * DIM_V))[c];
    float4 o; o.x = a.x + b.x; o.y = a.y + b.y; o.z = a.z + b.z; o.w = a.w + b.w;
    ((float4*)(y + (size_t)n * DIM_V))[c] = o;
  }
}

extern "C" void kernel_launch(void* const* d_in, const int* in_sizes, int n_in,
                              void* d_out, int out_size, void* d_ws, size_t ws_size,
                              hipStream_t stream) {
  if (ws_size < WS_FULL) return;
  const float* x      = (const float*)d_in[0];
  const float* rw     = (const float*)d_in[1];
  const float* keys   = (const float*)d_in[2];
  const float* bias   = (const float*)d_in[3];
  const float* fc_w   = (const float*)d_in[4];
  const float* proj_w = (const float*)d_in[5];
  const int*   depth  = (const int*)d_in[6];
  char* ws = (char*)d_ws;
  unsigned short* xb  = (unsigned short*)(ws + OFF_XB);
  unsigned short* wb  = (unsigned short*)(ws + OFF_WB);
  double* rk    = (double*)(ws + OFF_RK);
  double* kpp   = (double*)(ws + OFF_KPP);
  float*  ssq   = (float*)(ws + OFF_SSQ);
  int*    cnt   = (int*)(ws + OFF_CNT);
  int*    cur   = (int*)(ws + OFF_CUR);
  int*    tok   = (int*)(ws + OFF_TOK);
  float*  gsl   = (float*)(ws + OFF_GSL);
  int*    offp  = (int*)(ws + OFF_OFFP);
  int*    idx2  = (int*)(ws + OFF_IDX2);
  float*  g2    = (float*)(ws + OFF_G2);
  int*    inv   = (int*)(ws + OFF_INV);
  unsigned short* fcb = (unsigned short*)(ws + A_OFF_FCB);
  unsigned short* pjb = (unsigned short*)(ws + A_OFF_PJB);
  unsigned short* h2  = (unsigned short*)(ws + A_OFF_H2);
  float*  po    = (float*)(ws + A_OFF_PO);
  float*  y     = (float*)d_out;

  hipMemsetAsync(ws + ZERO_BEG, 0, ZERO_END - ZERO_BEG, stream);
  k_cvt_all<<<2048, 256, 0, stream>>>(x, rw, fc_w, proj_w, xb, wb, fcb, pjb);
  k_ropekeys<<<1, 512, 0, stream>>>(keys, depth, rk);
  k_colsum<<<dim3(4, 16), 256, 0, stream>>>(rw, rk, kpp);
  k_gemm<DIM_V, DIM_V, 0><<<dim3(32 * 8), 256, 0, stream>>>(xb, wb, offp, gsl, ssq);
  k_gate<<<1024, 256, 0, stream>>>(x, kpp, ssq, bias, idx2, g2, cnt);
  k_scatter<<<16, 256, 0, stream>>>(idx2, g2, cnt, cur, tok, gsl, inv, offp);
  k_fc256<<<dim3(44 * 16), 512, 0, stream>>>(xb, fcb, offp, tok, h2);
  k_gemm<HID, DIM_V, 1><<<dim3(72 * 8), 256, 0, stream>>>(h2, pjb, offp, gsl, po);
  k_combine<<<2048, 256, 0, stream>>>(po, inv, y);
}